// Round 1
// baseline (22800.912 us; speedup 1.0000x reference)
//
#include <hip/hip_runtime.h>
#include <math.h>

#define N_NODES 15000
#define NPAD    15040
#define E_EDGES 240000
#define IN_DIM  100
#define HID     128
#define N_ETYPES 13
#define N_STEPS  6
#define N_GRAPHS 64
#define N_CLASSES 10

// ---------------- utility kernels ----------------

__global__ __launch_bounds__(256) void k_zero(float* __restrict__ p, long n4) {
    long i = (long)blockIdx.x * 256 + threadIdx.x;
    if (i < n4) ((float4*)p)[i] = make_float4(0.f, 0.f, 0.f, 0.f);
}

__global__ __launch_bounds__(256) void k_init_h(const float* __restrict__ feat,
                                                float* __restrict__ h) {
    int idx = blockIdx.x * 256 + threadIdx.x;
    if (idx >= NPAD * HID) return;
    int n = idx >> 7, c = idx & 127;
    float v = 0.f;
    if (n < N_NODES && c < IN_DIM) v = feat[n * IN_DIM + c];
    h[idx] = v;
}

// WT[k*384 + j] = W[j*128 + k]  for both W_ih and W_hh
__global__ __launch_bounds__(256) void k_transpose(const float* __restrict__ Wih,
                                                   const float* __restrict__ Whh,
                                                   float* __restrict__ WihT,
                                                   float* __restrict__ WhhT) {
    int idx = blockIdx.x * 256 + threadIdx.x;
    if (idx >= 2 * 384 * HID) return;
    const float* Wsrc = (idx < 384 * HID) ? Wih : Whh;
    float*       Wdst = (idx < 384 * HID) ? WihT : WhhT;
    int i = (idx < 384 * HID) ? idx : idx - 384 * HID;
    int k = i / 384, j = i - k * 384;
    Wdst[i] = Wsrc[j * HID + k];
}

// ---------------- generic fp32 GEMM: C = A[Mx128] @ B[128xJ] + bias ----------------
// block: 64 rows x 128 cols (col tile j0 = blockIdx.y*128), z batches B/bias/C.
__global__ __launch_bounds__(256) void k_gemm(
    const float* __restrict__ A,    // [>=M x 128] (rows padded, no load guard)
    const float* __restrict__ B,    // [128 x J] row-major
    const float* __restrict__ bias, // [J]
    float* __restrict__ C,          // [M x ldC]
    int M, int J, int ldC,
    long sB, long sBias, long sC)
{
    __shared__ float bt[HID * HID]; // 64 KB: bt[k][j]
    int z = blockIdx.z;
    B    += (long)z * sB;
    bias += (long)z * sBias;
    C    += (long)z * sC;
    int j0   = blockIdx.y * 128;
    int row0 = blockIdx.x * 64;
    int tid  = threadIdx.x;

    for (int i = 0; i < 64; ++i) {
        int idx = i * 256 + tid;          // 0..16383
        int k = idx >> 7, j = idx & 127;
        bt[idx] = B[k * J + j0 + j];
    }
    __syncthreads();

    int jc = tid & 31;   // 4-col group
    int nc = tid >> 5;   // 8-row group
    const float4* bt4 = (const float4*)bt;
    const float4* A4  = (const float4*)(A + (long)(row0 + nc * 8) * HID);

    float acc[8][4] = {};
    for (int kb = 0; kb < 32; ++kb) {
        float4 av[8];
        #pragma unroll
        for (int i = 0; i < 8; ++i) av[i] = A4[i * 32 + kb];
        #pragma unroll
        for (int kk = 0; kk < 4; ++kk) {
            float4 wv = bt4[(kb * 4 + kk) * 32 + jc];
            #pragma unroll
            for (int i = 0; i < 8; ++i) {
                float a_ = (kk == 0) ? av[i].x : (kk == 1) ? av[i].y : (kk == 2) ? av[i].z : av[i].w;
                acc[i][0] = fmaf(a_, wv.x, acc[i][0]);
                acc[i][1] = fmaf(a_, wv.y, acc[i][1]);
                acc[i][2] = fmaf(a_, wv.z, acc[i][2]);
                acc[i][3] = fmaf(a_, wv.w, acc[i][3]);
            }
        }
    }

    float4 bv = *(const float4*)(bias + j0 + jc * 4);
    #pragma unroll
    for (int i = 0; i < 8; ++i) {
        int row = row0 + nc * 8 + i;
        if (row < M) {
            float4 o = make_float4(acc[i][0] + bv.x, acc[i][1] + bv.y,
                                   acc[i][2] + bv.z, acc[i][3] + bv.w);
            *(float4*)(C + (long)row * ldC + j0 + jc * 4) = o;
        }
    }
}

// ---------------- edge gather + scatter-add ----------------
__global__ __launch_bounds__(256) void k_scatter(
    const int* __restrict__ src, const int* __restrict__ dst, const int* __restrict__ et,
    const float* __restrict__ Wh, float* __restrict__ a)
{
    long idx = (long)blockIdx.x * 256 + threadIdx.x;
    if (idx >= (long)E_EDGES * HID) return;
    int e = (int)(idx >> 7);
    int c = (int)(idx & 127);
    int t = et[e], s = src[e], d = dst[e];
    float v = Wh[((long)t * NPAD + s) * HID + c];
    atomicAdd(&a[(long)d * HID + c], v);
}

// ---------------- GRU gates (in-place h update) ----------------
__global__ __launch_bounds__(256) void k_gates(
    const float* __restrict__ GI, const float* __restrict__ GH, float* __restrict__ h)
{
    int idx = blockIdx.x * 256 + threadIdx.x;
    if (idx >= N_NODES * HID) return;
    int n = idx >> 7, c = idx & 127;
    long b = (long)n * 384 + c;
    float ir = GI[b], iz = GI[b + 128], inn = GI[b + 256];
    float hr = GH[b], hz = GH[b + 128], hn  = GH[b + 256];
    float r  = 1.f / (1.f + expf(-(ir + hr)));
    float zg = 1.f / (1.f + expf(-(iz + hz)));
    float ng = tanhf(inn + r * hn);
    float ho = h[idx];
    h[idx] = (1.f - zg) * ng + zg * ho;
}

// ---------------- graph pooling + classifier ----------------
__global__ __launch_bounds__(256) void k_pool(const float* __restrict__ h,
                                              const int* __restrict__ gid,
                                              float* __restrict__ hg) {
    int idx = blockIdx.x * 256 + threadIdx.x;
    if (idx >= N_NODES * HID) return;
    int n = idx >> 7, c = idx & 127;
    atomicAdd(&hg[gid[n] * HID + c], h[idx]);
}

__global__ __launch_bounds__(640) void k_cls(const float* __restrict__ hg,
                                             const float* __restrict__ Wc,
                                             const float* __restrict__ bc,
                                             float* __restrict__ out) {
    int tid = threadIdx.x;
    if (tid >= N_GRAPHS * N_CLASSES) return;
    int g = tid / N_CLASSES, c = tid - g * N_CLASSES;
    float s = bc[c];
    for (int k = 0; k < HID; ++k) s = fmaf(hg[g * HID + k], Wc[c * HID + k], s);
    out[tid] = s;
}

// ---------------- launch ----------------
extern "C" void kernel_launch(void* const* d_in, const int* in_sizes, int n_in,
                              void* d_out, int out_size, void* d_ws, size_t ws_size,
                              hipStream_t stream) {
    const float* feat  = (const float*)d_in[0];
    const int*   src   = (const int*)d_in[1];
    const int*   dst   = (const int*)d_in[2];
    const int*   et    = (const int*)d_in[3];
    const int*   gid   = (const int*)d_in[4];
    const float* W_e   = (const float*)d_in[5];
    const float* b_e   = (const float*)d_in[6];
    const float* W_ih  = (const float*)d_in[7];
    const float* W_hh  = (const float*)d_in[8];
    const float* b_ih  = (const float*)d_in[9];
    const float* b_hh  = (const float*)d_in[10];
    const float* W_cls = (const float*)d_in[11];
    const float* b_cls = (const float*)d_in[12];
    float* out = (float*)d_out;

    float* ws   = (float*)d_ws;
    float* h    = ws;                                  // NPAD*128
    float* a    = h + (long)NPAD * HID;                // NPAD*128
    float* Wh   = a + (long)NPAD * HID;                // 13*NPAD*128
    float* GI   = Wh + (long)N_ETYPES * NPAD * HID;    // 15000*384
    float* GH   = GI + (long)N_NODES * 384;            // 15000*384
    float* WihT = GH + (long)N_NODES * 384;            // 128*384
    float* WhhT = WihT + 384 * HID;                    // 128*384
    float* hg   = WhhT + 384 * HID;                    // 64*128

    k_init_h<<<(NPAD * HID + 255) / 256, 256, 0, stream>>>(feat, h);
    k_transpose<<<(2 * 384 * HID + 255) / 256, 256, 0, stream>>>(W_ih, W_hh, WihT, WhhT);

    dim3 gE(235, 1, 13);   // etype GEMM: 235 row-blocks x 13 etypes
    dim3 gG(235, 3, 1);    // GRU GEMMs: 235 row-blocks x 3 col tiles
    long na4 = (long)NPAD * HID / 4;

    for (int step = 0; step < N_STEPS; ++step) {
        k_gemm<<<gE, 256, 0, stream>>>(h, W_e, b_e, Wh, N_NODES, HID, HID,
                                       (long)HID * HID, HID, (long)NPAD * HID);
        k_zero<<<(int)((na4 + 255) / 256), 256, 0, stream>>>(a, na4);
        k_scatter<<<(E_EDGES * HID) / 256, 256, 0, stream>>>(src, dst, et, Wh, a);
        k_gemm<<<gG, 256, 0, stream>>>(a, WihT, b_ih, GI, N_NODES, 384, 384, 0, 0, 0);
        k_gemm<<<gG, 256, 0, stream>>>(h, WhhT, b_hh, GH, N_NODES, 384, 384, 0, 0, 0);
        k_gates<<<(N_NODES * HID + 255) / 256, 256, 0, stream>>>(GI, GH, h);
    }

    k_zero<<<(N_GRAPHS * HID / 4 + 255) / 256, 256, 0, stream>>>(hg, N_GRAPHS * HID / 4);
    k_pool<<<(N_NODES * HID + 255) / 256, 256, 0, stream>>>(h, gid, hg);
    k_cls<<<1, 640, 0, stream>>>(hg, W_cls, b_cls, out);
}

// Round 3
// 788.861 us; speedup vs baseline: 28.9036x; 28.9036x over previous
//
#include <hip/hip_runtime.h>
#include <math.h>

#define N_NODES 15000
#define NPAD    15104      // 118*128
#define E_EDGES 240000
#define IN_DIM  100
#define HID     128
#define N_ETYPES 13
#define N_STEPS  6
#define N_GRAPHS 64
#define N_CLASSES 10

typedef short v8bf __attribute__((ext_vector_type(8)));
typedef float v4f  __attribute__((ext_vector_type(4)));

union FragU { uint4 u; v8bf b; };

static __device__ __forceinline__ float bf2f(unsigned short u) {
    union { unsigned int i; float f; } x; x.i = ((unsigned int)u) << 16; return x.f;
}
static __device__ __forceinline__ unsigned short f2bf(float f) {
    union { float f; unsigned int i; } x; x.f = f;
    unsigned int u = x.i;
    u = (u + 0x7fff + ((u >> 16) & 1)) >> 16;   // round-nearest-even
    return (unsigned short)u;
}

// ---------------- misc ----------------
__global__ __launch_bounds__(256) void k_zero(float* __restrict__ p, long n4) {
    long i = (long)blockIdx.x * 256 + threadIdx.x;
    if (i < n4) ((float4*)p)[i] = make_float4(0.f, 0.f, 0.f, 0.f);
}

// h32 fp32 [NPAD x 128] + bf16 hi/lo planes
__global__ __launch_bounds__(256) void k_init_h(const float* __restrict__ feat,
                                                float* __restrict__ h32,
                                                unsigned short* __restrict__ h_hi,
                                                unsigned short* __restrict__ h_lo) {
    int idx = blockIdx.x * 256 + threadIdx.x;
    if (idx >= NPAD * HID) return;
    int n = idx >> 7, c = idx & 127;
    float v = 0.f;
    if (n < N_NODES && c < IN_DIM) v = feat[n * IN_DIM + c];
    h32[idx] = v;
    unsigned short hi = f2bf(v);
    h_hi[idx] = hi;
    h_lo[idx] = f2bf(v - bf2f(hi));
}

// Weights -> bf16 hi/lo MFMA-fragment planes.
// Frag layout for B[128 x NC]: frag id = kcsub*NC + col (kcsub 0..15), 8 bf16 k=kcsub*8+j.
__global__ __launch_bounds__(256) void k_prepW(
    const float* __restrict__ W_e, const float* __restrict__ W_ih, const float* __restrict__ W_hh,
    unsigned short* __restrict__ WeH, unsigned short* __restrict__ WeL,
    unsigned short* __restrict__ WihH, unsigned short* __restrict__ WihL,
    unsigned short* __restrict__ WhhH, unsigned short* __restrict__ WhhL)
{
    int f = blockIdx.x * 256 + threadIdx.x;
    const int NE = N_ETYPES * 2048;
    const int NG = 16 * 384;
    unsigned short th[8], tl[8];
    const float* srcp; unsigned short *dh, *dl; long off;
    if (f < NE) {
        int t = f >> 11, r = f & 2047, kcsub = r >> 7, c = r & 127;
        #pragma unroll
        for (int j = 0; j < 8; ++j) {
            float w = W_e[(long)t * 16384 + (kcsub * 8 + j) * 128 + c];
            th[j] = f2bf(w); tl[j] = f2bf(w - bf2f(th[j]));
        }
        off = (long)t * 16384 + ((kcsub << 7) + c) * 8;
        *(uint4*)(WeH + off) = *(uint4*)th;
        *(uint4*)(WeL + off) = *(uint4*)tl;
    } else if (f < NE + 2 * NG) {
        int f2 = f - NE;
        srcp = (f2 < NG) ? W_ih : W_hh;
        dh   = (f2 < NG) ? WihH : WhhH;
        dl   = (f2 < NG) ? WihL : WhhL;
        int g = (f2 < NG) ? f2 : f2 - NG;
        int kcsub = g / 384, c = g - kcsub * 384;
        #pragma unroll
        for (int j = 0; j < 8; ++j) {
            float w = srcp[(long)c * 128 + kcsub * 8 + j];   // B[k][c] = W[c][k]
            th[j] = f2bf(w); tl[j] = f2bf(w - bf2f(th[j]));
        }
        off = ((long)kcsub * 384 + c) * 8;
        *(uint4*)(dh + off) = *(uint4*)th;
        *(uint4*)(dl + off) = *(uint4*)tl;
    }
}

// ---------------- CSR build ----------------
__global__ __launch_bounds__(256) void k_count(const int* __restrict__ dst, int* __restrict__ deg) {
    int e = blockIdx.x * 256 + threadIdx.x;
    if (e < E_EDGES) atomicAdd(&deg[dst[e]], 1);
}

__global__ __launch_bounds__(1024) void k_scan(const int* __restrict__ deg,
                                               int* __restrict__ rowptr, int* __restrict__ cursor) {
    __shared__ int part[1024];
    int tid = threadIdx.x;
    const int CH = 15;
    int base = tid * CH;
    int local[CH]; int s = 0;
    #pragma unroll
    for (int i = 0; i < CH; ++i) {
        int d = (base + i < NPAD) ? deg[base + i] : 0;
        local[i] = s; s += d;
    }
    part[tid] = s; __syncthreads();
    for (int off = 1; off < 1024; off <<= 1) {
        int v = (tid >= off) ? part[tid - off] : 0;
        __syncthreads();
        part[tid] += v;
        __syncthreads();
    }
    int excl = (tid > 0) ? part[tid - 1] : 0;
    #pragma unroll
    for (int i = 0; i < CH; ++i)
        if (base + i < NPAD) { rowptr[base + i] = excl + local[i]; cursor[base + i] = excl + local[i]; }
    if (tid == 0) rowptr[NPAD] = part[1023];
}

__global__ __launch_bounds__(256) void k_fill(const int* __restrict__ src, const int* __restrict__ dst,
                                              const int* __restrict__ et, int* __restrict__ cursor,
                                              int* __restrict__ eidx) {
    int e = blockIdx.x * 256 + threadIdx.x;
    if (e >= E_EDGES) return;
    int d = dst[e];
    int pos = atomicAdd(&cursor[d], 1);
    eidx[pos] = et[e] * NPAD + src[e];
}

// ---------------- split-bf16 MFMA GEMM: C = A @ B + bias (fp32 out) ----------------
// C ~= Ahi@Bhi + Alo@Bhi + Ahi@Blo. grid: (118, NC/128, z). 256 thr = 4 waves; 128x128/block.
__global__ __launch_bounds__(256) void k_mgemm(
    const unsigned short* __restrict__ Ahi, const unsigned short* __restrict__ Alo,
    const unsigned short* __restrict__ Bhi, const unsigned short* __restrict__ Blo,
    const float* __restrict__ bias, float* __restrict__ C,
    int M, int NC, int ldC, long sB, long sBias, long sC)
{
    __shared__ unsigned short blds[2][16 * 128 * 8];   // 64 KB
    int z = blockIdx.z;
    Bhi += (long)z * sB; Blo += (long)z * sB;
    bias += (long)z * sBias; C += (long)z * sC;
    int j0 = blockIdx.y * 128;
    int tid = threadIdx.x;

    {
        const uint4* sh = (const uint4*)Bhi;
        const uint4* sl = (const uint4*)Blo;
        uint4* dh = (uint4*)blds[0];
        uint4* dl = (uint4*)blds[1];
        #pragma unroll
        for (int it = 0; it < 8; ++it) {
            int f = it * 256 + tid;
            int kcsub = f >> 7, c = f & 127;
            long sidx = (long)kcsub * NC + j0 + c;
            dh[f] = sh[sidx];
            dl[f] = sl[sidx];
        }
    }
    __syncthreads();

    int lane = tid & 63, w = tid >> 6;
    int r0 = blockIdx.x * 128 + w * 32;
    int l15 = lane & 15, lsub = lane >> 4;

    FragU ah[2][4], al[2][4];
    const char* Ahb = (const char*)Ahi;
    const char* Alb = (const char*)Alo;
    #pragma unroll
    for (int fr = 0; fr < 2; ++fr)
        #pragma unroll
        for (int kc = 0; kc < 4; ++kc) {
            long boff = (long)(r0 + fr * 16 + l15) * 256 + kc * 64 + lsub * 16;
            ah[fr][kc].u = *(const uint4*)(Ahb + boff);
            al[fr][kc].u = *(const uint4*)(Alb + boff);
        }

    v4f acc[2][8];
    #pragma unroll
    for (int fr = 0; fr < 2; ++fr)
        #pragma unroll
        for (int c8 = 0; c8 < 8; ++c8) acc[fr][c8] = (v4f)(0.f);

    const uint4* blh = (const uint4*)blds[0];
    const uint4* bll = (const uint4*)blds[1];
    #pragma unroll
    for (int kc = 0; kc < 4; ++kc) {
        #pragma unroll
        for (int c8 = 0; c8 < 8; ++c8) {
            int bi = (kc * 4 + lsub) * 128 + c8 * 16 + l15;
            FragU bh, bl; bh.u = blh[bi]; bl.u = bll[bi];
            #pragma unroll
            for (int fr = 0; fr < 2; ++fr) {
                acc[fr][c8] = __builtin_amdgcn_mfma_f32_16x16x32_bf16(ah[fr][kc].b, bh.b, acc[fr][c8], 0, 0, 0);
                acc[fr][c8] = __builtin_amdgcn_mfma_f32_16x16x32_bf16(al[fr][kc].b, bh.b, acc[fr][c8], 0, 0, 0);
                acc[fr][c8] = __builtin_amdgcn_mfma_f32_16x16x32_bf16(ah[fr][kc].b, bl.b, acc[fr][c8], 0, 0, 0);
            }
        }
    }

    #pragma unroll
    for (int fr = 0; fr < 2; ++fr) {
        int rbase = r0 + fr * 16 + lsub * 4;        // C/D: col = lane&15, row = (lane>>4)*4 + i
        #pragma unroll
        for (int c8 = 0; c8 < 8; ++c8) {
            int col = j0 + c8 * 16 + l15;
            float bv = bias[col];
            #pragma unroll
            for (int i = 0; i < 4; ++i) {
                int row = rbase + i;
                if (row < M) C[(long)row * ldC + col] = acc[fr][c8][i] + bv;
            }
        }
    }
}

// ---------------- CSR aggregation: a[d] = sum Wh[eidx] (fp32 in, hi/lo bf16 out) ----------------
__global__ __launch_bounds__(256) void k_agg(
    const int* __restrict__ rowptr, const int* __restrict__ eidx,
    const float* __restrict__ Wh,
    unsigned int* __restrict__ a_hi, unsigned int* __restrict__ a_lo)
{
    int d = blockIdx.x * 4 + (threadIdx.x >> 6);
    if (d >= NPAD) return;
    int lane = threadIdx.x & 63;
    int s = rowptr[d], e = rowptr[d + 1];
    float a0 = 0.f, a1 = 0.f;
    for (int i = s; i < e; ++i) {
        int w = eidx[i];
        float2 v = ((const float2*)(Wh + (long)w * 128))[lane];
        a0 += v.x; a1 += v.y;
    }
    unsigned short h0 = f2bf(a0), h1 = f2bf(a1);
    unsigned short l0 = f2bf(a0 - bf2f(h0)), l1 = f2bf(a1 - bf2f(h1));
    a_hi[(long)d * 64 + lane] = (unsigned int)h0 | ((unsigned int)h1 << 16);
    a_lo[(long)d * 64 + lane] = (unsigned int)l0 | ((unsigned int)l1 << 16);
}

// ---------------- GRU gates (fp32 carry; emit bf16 hi/lo for next matmuls) ----------------
__global__ __launch_bounds__(256) void k_gates(
    const float* __restrict__ GI, const float* __restrict__ GH,
    float* __restrict__ h32,
    unsigned short* __restrict__ h_hi, unsigned short* __restrict__ h_lo)
{
    int idx = blockIdx.x * 256 + threadIdx.x;
    if (idx >= N_NODES * HID) return;
    int n = idx >> 7, c = idx & 127;
    long b = (long)n * 384 + c;
    float ir = GI[b], iz = GI[b + 128], inn = GI[b + 256];
    float hr = GH[b], hz = GH[b + 128], hn  = GH[b + 256];
    float r  = 1.f / (1.f + expf(-(ir + hr)));
    float zg = 1.f / (1.f + expf(-(iz + hz)));
    float ng = tanhf(inn + r * hn);
    float ho = h32[idx];
    float hv = (1.f - zg) * ng + zg * ho;
    h32[idx] = hv;
    unsigned short hi = f2bf(hv);
    h_hi[idx] = hi;
    h_lo[idx] = f2bf(hv - bf2f(hi));
}

// ---------------- pooling + classifier ----------------
__global__ __launch_bounds__(256) void k_pool(const float* __restrict__ h32,
                                              const int* __restrict__ gid,
                                              float* __restrict__ hg) {
    int idx = blockIdx.x * 256 + threadIdx.x;
    if (idx >= N_NODES * HID) return;
    int n = idx >> 7, c = idx & 127;
    atomicAdd(&hg[gid[n] * HID + c], h32[idx]);
}

__global__ __launch_bounds__(640) void k_cls(const float* __restrict__ hg,
                                             const float* __restrict__ Wc,
                                             const float* __restrict__ bc,
                                             float* __restrict__ out) {
    int tid = threadIdx.x;
    if (tid >= N_GRAPHS * N_CLASSES) return;
    int g = tid / N_CLASSES, c = tid - g * N_CLASSES;
    float s = bc[c];
    for (int k = 0; k < HID; ++k) s = fmaf(hg[g * HID + k], Wc[c * HID + k], s);
    out[tid] = s;
}

// ---------------- launch ----------------
extern "C" void kernel_launch(void* const* d_in, const int* in_sizes, int n_in,
                              void* d_out, int out_size, void* d_ws, size_t ws_size,
                              hipStream_t stream) {
    const float* feat  = (const float*)d_in[0];
    const int*   src   = (const int*)d_in[1];
    const int*   dst   = (const int*)d_in[2];
    const int*   et    = (const int*)d_in[3];
    const int*   gid   = (const int*)d_in[4];
    const float* W_e   = (const float*)d_in[5];
    const float* b_e   = (const float*)d_in[6];
    const float* W_ih  = (const float*)d_in[7];
    const float* W_hh  = (const float*)d_in[8];
    const float* b_ih  = (const float*)d_in[9];
    const float* b_hh  = (const float*)d_in[10];
    const float* W_cls = (const float*)d_in[11];
    const float* b_cls = (const float*)d_in[12];
    float* out = (float*)d_out;

    char* p = (char*)d_ws;
    auto alloc = [&](size_t bytes) { char* r = p; p += (bytes + 255) & ~(size_t)255; return r; };
    float*          h32  = (float*)alloc((size_t)NPAD * 128 * 4);
    unsigned short* h_hi = (unsigned short*)alloc((size_t)NPAD * 128 * 2);
    unsigned short* h_lo = (unsigned short*)alloc((size_t)NPAD * 128 * 2);
    unsigned short* a_hi = (unsigned short*)alloc((size_t)NPAD * 128 * 2);
    unsigned short* a_lo = (unsigned short*)alloc((size_t)NPAD * 128 * 2);
    float*          Wh   = (float*)alloc((size_t)N_ETYPES * NPAD * 128 * 4);
    float*          GI   = (float*)alloc((size_t)N_NODES * 384 * 4);
    float*          GH   = (float*)alloc((size_t)N_NODES * 384 * 4);
    unsigned short* WeH  = (unsigned short*)alloc((size_t)N_ETYPES * 16384 * 2);
    unsigned short* WeL  = (unsigned short*)alloc((size_t)N_ETYPES * 16384 * 2);
    unsigned short* WihH = (unsigned short*)alloc((size_t)16 * 384 * 8 * 2);
    unsigned short* WihL = (unsigned short*)alloc((size_t)16 * 384 * 8 * 2);
    unsigned short* WhhH = (unsigned short*)alloc((size_t)16 * 384 * 8 * 2);
    unsigned short* WhhL = (unsigned short*)alloc((size_t)16 * 384 * 8 * 2);
    int* deg    = (int*)alloc((size_t)NPAD * 4);
    int* rowptr = (int*)alloc((size_t)(NPAD + 1) * 4);
    int* cursor = (int*)alloc((size_t)NPAD * 4);
    int* eidx   = (int*)alloc((size_t)E_EDGES * 4);
    float* hg   = (float*)alloc((size_t)N_GRAPHS * HID * 4);

    k_init_h<<<(NPAD * HID + 255) / 256, 256, 0, stream>>>(feat, h32, h_hi, h_lo);
    k_prepW<<<(N_ETYPES * 2048 + 2 * 16 * 384 + 255) / 256, 256, 0, stream>>>(
        W_e, W_ih, W_hh, WeH, WeL, WihH, WihL, WhhH, WhhL);
    k_zero<<<(NPAD / 4 + 255) / 256, 256, 0, stream>>>((float*)deg, NPAD / 4);
    k_count<<<(E_EDGES + 255) / 256, 256, 0, stream>>>(dst, deg);
    k_scan<<<1, 1024, 0, stream>>>(deg, rowptr, cursor);
    k_fill<<<(E_EDGES + 255) / 256, 256, 0, stream>>>(src, dst, et, cursor, eidx);

    dim3 gE(118, 1, N_ETYPES);
    dim3 gG(118, 3, 1);
    for (int step = 0; step < N_STEPS; ++step) {
        k_mgemm<<<gE, 256, 0, stream>>>(h_hi, h_lo, WeH, WeL, b_e, Wh,
                                        N_NODES, 128, 128, 16384, 128, (long)NPAD * 128);
        k_agg<<<NPAD / 4, 256, 0, stream>>>(rowptr, eidx, Wh,
                                            (unsigned int*)a_hi, (unsigned int*)a_lo);
        k_mgemm<<<gG, 256, 0, stream>>>(a_hi, a_lo, WihH, WihL, b_ih, GI,
                                        N_NODES, 384, 384, 0, 0, 0);
        k_mgemm<<<gG, 256, 0, stream>>>(h_hi, h_lo, WhhH, WhhL, b_hh, GH,
                                        N_NODES, 384, 384, 0, 0, 0);
        k_gates<<<(N_NODES * HID + 255) / 256, 256, 0, stream>>>(GI, GH, h32, h_hi, h_lo);
    }

    k_zero<<<(N_GRAPHS * HID / 4 + 255) / 256, 256, 0, stream>>>(hg, N_GRAPHS * HID / 4);
    k_pool<<<(N_NODES * HID + 255) / 256, 256, 0, stream>>>(h32, gid, hg);
    k_cls<<<1, 640, 0, stream>>>(hg, W_cls, b_cls, out);
}

// Round 4
// 661.938 us; speedup vs baseline: 34.4457x; 1.1917x over previous
//
#include <hip/hip_runtime.h>
#include <math.h>

#define N_NODES 15000
#define NPAD    15104      // 118*128
#define E_EDGES 240000
#define IN_DIM  100
#define HID     128
#define N_ETYPES 13
#define N_STEPS  6
#define N_GRAPHS 64
#define N_CLASSES 10

typedef short v8bf __attribute__((ext_vector_type(8)));
typedef float v4f  __attribute__((ext_vector_type(4)));

union FragU { uint4 u; v8bf b; };

static __device__ __forceinline__ float bf2f(unsigned short u) {
    union { unsigned int i; float f; } x; x.i = ((unsigned int)u) << 16; return x.f;
}
static __device__ __forceinline__ unsigned short f2bf(float f) {
    union { float f; unsigned int i; } x; x.f = f;
    unsigned int u = x.i;
    u = (u + 0x7fff + ((u >> 16) & 1)) >> 16;   // round-nearest-even
    return (unsigned short)u;
}
static __device__ __forceinline__ float sigm(float x) { return 1.f / (1.f + expf(-x)); }

// ---------------- misc ----------------
__global__ __launch_bounds__(256) void k_zero(float* __restrict__ p, long n4) {
    long i = (long)blockIdx.x * 256 + threadIdx.x;
    if (i < n4) ((float4*)p)[i] = make_float4(0.f, 0.f, 0.f, 0.f);
}

__global__ __launch_bounds__(256) void k_init_h(const float* __restrict__ feat,
                                                float* __restrict__ h32,
                                                unsigned short* __restrict__ h_hi,
                                                unsigned short* __restrict__ h_lo) {
    int idx = blockIdx.x * 256 + threadIdx.x;
    if (idx >= NPAD * HID) return;
    int n = idx >> 7, c = idx & 127;
    float v = 0.f;
    if (n < N_NODES && c < IN_DIM) v = feat[n * IN_DIM + c];
    h32[idx] = v;
    unsigned short hi = f2bf(v);
    h_hi[idx] = hi;
    h_lo[idx] = f2bf(v - bf2f(hi));
}

// Weights -> bf16 hi/lo MFMA-fragment planes.
// Frag layout for B[128 x NC]: frag id = kcsub*NC + col (kcsub 0..15), 8 bf16 k=kcsub*8+j.
__global__ __launch_bounds__(256) void k_prepW(
    const float* __restrict__ W_e, const float* __restrict__ W_ih, const float* __restrict__ W_hh,
    unsigned short* __restrict__ WeH, unsigned short* __restrict__ WeL,
    unsigned short* __restrict__ WihH, unsigned short* __restrict__ WihL,
    unsigned short* __restrict__ WhhH, unsigned short* __restrict__ WhhL)
{
    int f = blockIdx.x * 256 + threadIdx.x;
    const int NE = N_ETYPES * 2048;
    const int NG = 16 * 384;
    unsigned short th[8], tl[8];
    if (f < NE) {
        int t = f >> 11, r = f & 2047, kcsub = r >> 7, c = r & 127;
        #pragma unroll
        for (int j = 0; j < 8; ++j) {
            float w = W_e[(long)t * 16384 + (kcsub * 8 + j) * 128 + c];
            th[j] = f2bf(w); tl[j] = f2bf(w - bf2f(th[j]));
        }
        long off = (long)t * 16384 + ((kcsub << 7) + c) * 8;
        *(uint4*)(WeH + off) = *(uint4*)th;
        *(uint4*)(WeL + off) = *(uint4*)tl;
    } else if (f < NE + 2 * NG) {
        int f2 = f - NE;
        const float* srcp = (f2 < NG) ? W_ih : W_hh;
        unsigned short* dh = (f2 < NG) ? WihH : WhhH;
        unsigned short* dl = (f2 < NG) ? WihL : WhhL;
        int g = (f2 < NG) ? f2 : f2 - NG;
        int kcsub = g / 384, c = g - kcsub * 384;
        #pragma unroll
        for (int j = 0; j < 8; ++j) {
            float w = srcp[(long)c * 128 + kcsub * 8 + j];   // B[k][c] = W[c][k]
            th[j] = f2bf(w); tl[j] = f2bf(w - bf2f(th[j]));
        }
        long off = ((long)kcsub * 384 + c) * 8;
        *(uint4*)(dh + off) = *(uint4*)th;
        *(uint4*)(dl + off) = *(uint4*)tl;
    }
}

// ---------------- CSR build ----------------
__global__ __launch_bounds__(256) void k_count(const int* __restrict__ dst, int* __restrict__ deg) {
    int e = blockIdx.x * 256 + threadIdx.x;
    if (e < E_EDGES) atomicAdd(&deg[dst[e]], 1);
}

__global__ __launch_bounds__(1024) void k_scan(const int* __restrict__ deg,
                                               int* __restrict__ rowptr, int* __restrict__ cursor) {
    __shared__ int part[1024];
    int tid = threadIdx.x;
    const int CH = 15;
    int base = tid * CH;
    int local[CH]; int s = 0;
    #pragma unroll
    for (int i = 0; i < CH; ++i) {
        int d = (base + i < NPAD) ? deg[base + i] : 0;
        local[i] = s; s += d;
    }
    part[tid] = s; __syncthreads();
    for (int off = 1; off < 1024; off <<= 1) {
        int v = (tid >= off) ? part[tid - off] : 0;
        __syncthreads();
        part[tid] += v;
        __syncthreads();
    }
    int excl = (tid > 0) ? part[tid - 1] : 0;
    #pragma unroll
    for (int i = 0; i < CH; ++i)
        if (base + i < NPAD) { rowptr[base + i] = excl + local[i]; cursor[base + i] = excl + local[i]; }
    if (tid == 0) rowptr[NPAD] = part[1023];
}

__global__ __launch_bounds__(256) void k_fill(const int* __restrict__ src, const int* __restrict__ dst,
                                              const int* __restrict__ et, int* __restrict__ cursor,
                                              int* __restrict__ eidx) {
    int e = blockIdx.x * 256 + threadIdx.x;
    if (e >= E_EDGES) return;
    int d = dst[e];
    int pos = atomicAdd(&cursor[d], 1);
    eidx[pos] = et[e] * NPAD + src[e];
}

// ---------------- etype GEMM: Wh[t] = h @ W_e[t] + b_e[t] (bf16 out, no LDS) ----------------
// 1-D grid 118*13; etype-fastest decode + bijective XCD chunk swizzle.
__global__ __launch_bounds__(256) void k_egemm(
    const unsigned short* __restrict__ Ahi, const unsigned short* __restrict__ Alo,
    const uint4* __restrict__ BH, const uint4* __restrict__ BL,
    const float* __restrict__ bias, unsigned short* __restrict__ C)
{
    const int NW = 118 * N_ETYPES;          // 1534
    const int q = NW / 8, r8 = NW % 8;      // 191, 6
    int bid = blockIdx.x;
    int xcd = bid & 7, ii = bid >> 3;
    int lid = (xcd < r8 ? xcd * (q + 1) : r8 * (q + 1) + (xcd - r8) * q) + ii;
    int rg = lid / N_ETYPES, t = lid - rg * N_ETYPES;

    int tid = threadIdx.x, lane = tid & 63, w = tid >> 6;
    int r0 = rg * 128 + w * 32;
    int l15 = lane & 15, lsub = lane >> 4;

    const uint4* bh = BH + t * 2048;
    const uint4* bl = BL + t * 2048;

    FragU ah[2][4], al[2][4];
    const char* Ahb = (const char*)Ahi;
    const char* Alb = (const char*)Alo;
    #pragma unroll
    for (int fr = 0; fr < 2; ++fr)
        #pragma unroll
        for (int kc = 0; kc < 4; ++kc) {
            long boff = (long)(r0 + fr * 16 + l15) * 256 + kc * 64 + lsub * 16;
            ah[fr][kc].u = *(const uint4*)(Ahb + boff);
            al[fr][kc].u = *(const uint4*)(Alb + boff);
        }

    v4f acc[2][8];
    #pragma unroll
    for (int fr = 0; fr < 2; ++fr)
        #pragma unroll
        for (int c8 = 0; c8 < 8; ++c8) acc[fr][c8] = (v4f)(0.f);

    #pragma unroll
    for (int kc = 0; kc < 4; ++kc)
        #pragma unroll
        for (int c8 = 0; c8 < 8; ++c8) {
            int bi = (kc * 4 + lsub) * 128 + c8 * 16 + l15;
            FragU bhf, blf; bhf.u = bh[bi]; blf.u = bl[bi];
            #pragma unroll
            for (int fr = 0; fr < 2; ++fr) {
                acc[fr][c8] = __builtin_amdgcn_mfma_f32_16x16x32_bf16(ah[fr][kc].b, bhf.b, acc[fr][c8], 0, 0, 0);
                acc[fr][c8] = __builtin_amdgcn_mfma_f32_16x16x32_bf16(al[fr][kc].b, bhf.b, acc[fr][c8], 0, 0, 0);
                acc[fr][c8] = __builtin_amdgcn_mfma_f32_16x16x32_bf16(ah[fr][kc].b, blf.b, acc[fr][c8], 0, 0, 0);
            }
        }

    const float* bs = bias + t * 128;
    unsigned short* Ct = C + (long)t * NPAD * 128;
    #pragma unroll
    for (int fr = 0; fr < 2; ++fr) {
        int rbase = r0 + fr * 16 + lsub * 4;        // C/D: col = lane&15, row = (lane>>4)*4 + i
        #pragma unroll
        for (int c8 = 0; c8 < 8; ++c8) {
            int col = c8 * 16 + l15;
            float bv = bs[col];
            #pragma unroll
            for (int i = 0; i < 4; ++i) {
                int row = rbase + i;
                if (row < N_NODES) Ct[(long)row * 128 + col] = f2bf(acc[fr][c8][i] + bv);
            }
        }
    }
}

// ---------------- merged GRU GEMMs: z=0: GI = a@WihT, z=1: GH = h@WhhT (bf16 out) ----------------
__global__ __launch_bounds__(256) void k_ggemm(
    const unsigned short* __restrict__ A0h, const unsigned short* __restrict__ A0l,
    const unsigned short* __restrict__ A1h, const unsigned short* __restrict__ A1l,
    const uint4* __restrict__ B0H, const uint4* __restrict__ B0L,
    const uint4* __restrict__ B1H, const uint4* __restrict__ B1L,
    const float* __restrict__ bias0, const float* __restrict__ bias1,
    unsigned short* __restrict__ C0, unsigned short* __restrict__ C1)
{
    int z = blockIdx.z;
    const unsigned short* Ahi = z ? A1h : A0h;
    const unsigned short* Alo = z ? A1l : A0l;
    const uint4* BH = z ? B1H : B0H;
    const uint4* BL = z ? B1L : B0L;
    const float* bias = z ? bias1 : bias0;
    unsigned short* C = z ? C1 : C0;

    int j0 = blockIdx.y * 128;
    int tid = threadIdx.x, lane = tid & 63, w = tid >> 6;
    int r0 = blockIdx.x * 128 + w * 32;
    int l15 = lane & 15, lsub = lane >> 4;

    FragU ah[2][4], al[2][4];
    const char* Ahb = (const char*)Ahi;
    const char* Alb = (const char*)Alo;
    #pragma unroll
    for (int fr = 0; fr < 2; ++fr)
        #pragma unroll
        for (int kc = 0; kc < 4; ++kc) {
            long boff = (long)(r0 + fr * 16 + l15) * 256 + kc * 64 + lsub * 16;
            ah[fr][kc].u = *(const uint4*)(Ahb + boff);
            al[fr][kc].u = *(const uint4*)(Alb + boff);
        }

    v4f acc[2][8];
    #pragma unroll
    for (int fr = 0; fr < 2; ++fr)
        #pragma unroll
        for (int c8 = 0; c8 < 8; ++c8) acc[fr][c8] = (v4f)(0.f);

    #pragma unroll
    for (int kc = 0; kc < 4; ++kc)
        #pragma unroll
        for (int c8 = 0; c8 < 8; ++c8) {
            int bi = (kc * 4 + lsub) * 384 + j0 + c8 * 16 + l15;
            FragU bhf, blf; bhf.u = BH[bi]; blf.u = BL[bi];
            #pragma unroll
            for (int fr = 0; fr < 2; ++fr) {
                acc[fr][c8] = __builtin_amdgcn_mfma_f32_16x16x32_bf16(ah[fr][kc].b, bhf.b, acc[fr][c8], 0, 0, 0);
                acc[fr][c8] = __builtin_amdgcn_mfma_f32_16x16x32_bf16(al[fr][kc].b, bhf.b, acc[fr][c8], 0, 0, 0);
                acc[fr][c8] = __builtin_amdgcn_mfma_f32_16x16x32_bf16(ah[fr][kc].b, blf.b, acc[fr][c8], 0, 0, 0);
            }
        }

    #pragma unroll
    for (int fr = 0; fr < 2; ++fr) {
        int rbase = r0 + fr * 16 + lsub * 4;
        #pragma unroll
        for (int c8 = 0; c8 < 8; ++c8) {
            int col = j0 + c8 * 16 + l15;
            float bv = bias[col];
            #pragma unroll
            for (int i = 0; i < 4; ++i) {
                int row = rbase + i;
                if (row < N_NODES) C[(long)row * 384 + col] = f2bf(acc[fr][c8][i] + bv);
            }
        }
    }
}

// ---------------- CSR aggregation: a[d] = sum Wh[eidx] (bf16 in, fp32 acc, hi/lo out) ----------------
__global__ __launch_bounds__(256) void k_agg(
    const int* __restrict__ rowptr, const int* __restrict__ eidx,
    const unsigned int* __restrict__ Wh,                 // bf16 pairs
    unsigned int* __restrict__ a_hi, unsigned int* __restrict__ a_lo)
{
    int d = blockIdx.x * 4 + (threadIdx.x >> 6);
    if (d >= NPAD) return;
    int lane = threadIdx.x & 63;
    int s = rowptr[d], e = rowptr[d + 1];
    float a0 = 0.f, a1 = 0.f, b0 = 0.f, b1 = 0.f;
    int i = s;
    for (; i + 1 < e; i += 2) {
        int w0 = eidx[i], w1 = eidx[i + 1];
        unsigned int v0 = Wh[(long)w0 * 64 + lane];
        unsigned int v1 = Wh[(long)w1 * 64 + lane];
        a0 += bf2f((unsigned short)(v0 & 0xffff));
        a1 += bf2f((unsigned short)(v0 >> 16));
        b0 += bf2f((unsigned short)(v1 & 0xffff));
        b1 += bf2f((unsigned short)(v1 >> 16));
    }
    if (i < e) {
        unsigned int v0 = Wh[(long)eidx[i] * 64 + lane];
        a0 += bf2f((unsigned short)(v0 & 0xffff));
        a1 += bf2f((unsigned short)(v0 >> 16));
    }
    a0 += b0; a1 += b1;
    unsigned short h0 = f2bf(a0), h1 = f2bf(a1);
    unsigned short l0 = f2bf(a0 - bf2f(h0)), l1 = f2bf(a1 - bf2f(h1));
    a_hi[(long)d * 64 + lane] = (unsigned int)h0 | ((unsigned int)h1 << 16);
    a_lo[(long)d * 64 + lane] = (unsigned int)l0 | ((unsigned int)l1 << 16);
}

// ---------------- GRU gates (fp32 carry; bf16 hi/lo planes out) ----------------
__global__ __launch_bounds__(256) void k_gates(
    const unsigned short* __restrict__ GI, const unsigned short* __restrict__ GH,
    float* __restrict__ h32,
    unsigned int* __restrict__ h_hi, unsigned int* __restrict__ h_lo)
{
    int idx = blockIdx.x * 256 + threadIdx.x;       // one uint = 2 channels
    if (idx >= N_NODES * 64) return;
    int n = idx >> 6, c2 = idx & 63;
    const unsigned int* gi = (const unsigned int*)(GI + (long)n * 384);
    const unsigned int* gh = (const unsigned int*)(GH + (long)n * 384);
    unsigned int uir = gi[c2], uiz = gi[c2 + 64], uin = gi[c2 + 128];
    unsigned int uhr = gh[c2], uhz = gh[c2 + 64], uhn = gh[c2 + 128];
    float2 ho = ((float2*)h32)[idx];
    float hv[2];
    #pragma unroll
    for (int p = 0; p < 2; ++p) {
        int sh = p * 16;
        float ir = bf2f((unsigned short)(uir >> sh)), iz = bf2f((unsigned short)(uiz >> sh)),
              inn = bf2f((unsigned short)(uin >> sh));
        float hr = bf2f((unsigned short)(uhr >> sh)), hz = bf2f((unsigned short)(uhz >> sh)),
              hn = bf2f((unsigned short)(uhn >> sh));
        float rr = sigm(ir + hr);
        float zg = sigm(iz + hz);
        float ng = tanhf(inn + rr * hn);
        float hov = p ? ho.y : ho.x;
        hv[p] = (1.f - zg) * ng + zg * hov;
    }
    ((float2*)h32)[idx] = make_float2(hv[0], hv[1]);
    unsigned short hi0 = f2bf(hv[0]), hi1 = f2bf(hv[1]);
    h_hi[idx] = (unsigned int)hi0 | ((unsigned int)hi1 << 16);
    unsigned short lo0 = f2bf(hv[0] - bf2f(hi0)), lo1 = f2bf(hv[1] - bf2f(hi1));
    h_lo[idx] = (unsigned int)lo0 | ((unsigned int)lo1 << 16);
}

// ---------------- pooling + classifier ----------------
__global__ __launch_bounds__(256) void k_pool(const float* __restrict__ h32,
                                              const int* __restrict__ gid,
                                              float* __restrict__ hg) {
    int idx = blockIdx.x * 256 + threadIdx.x;
    if (idx >= N_NODES * HID) return;
    int n = idx >> 7, c = idx & 127;
    atomicAdd(&hg[gid[n] * HID + c], h32[idx]);
}

__global__ __launch_bounds__(640) void k_cls(const float* __restrict__ hg,
                                             const float* __restrict__ Wc,
                                             const float* __restrict__ bc,
                                             float* __restrict__ out) {
    int tid = threadIdx.x;
    if (tid >= N_GRAPHS * N_CLASSES) return;
    int g = tid / N_CLASSES, c = tid - g * N_CLASSES;
    float s = bc[c];
    for (int k = 0; k < HID; ++k) s = fmaf(hg[g * HID + k], Wc[c * HID + k], s);
    out[tid] = s;
}

// ---------------- launch ----------------
extern "C" void kernel_launch(void* const* d_in, const int* in_sizes, int n_in,
                              void* d_out, int out_size, void* d_ws, size_t ws_size,
                              hipStream_t stream) {
    const float* feat  = (const float*)d_in[0];
    const int*   src   = (const int*)d_in[1];
    const int*   dst   = (const int*)d_in[2];
    const int*   et    = (const int*)d_in[3];
    const int*   gid   = (const int*)d_in[4];
    const float* W_e   = (const float*)d_in[5];
    const float* b_e   = (const float*)d_in[6];
    const float* W_ih  = (const float*)d_in[7];
    const float* W_hh  = (const float*)d_in[8];
    const float* b_ih  = (const float*)d_in[9];
    const float* b_hh  = (const float*)d_in[10];
    const float* W_cls = (const float*)d_in[11];
    const float* b_cls = (const float*)d_in[12];
    float* out = (float*)d_out;

    char* p = (char*)d_ws;
    auto alloc = [&](size_t bytes) { char* r = p; p += (bytes + 255) & ~(size_t)255; return r; };
    float*          h32  = (float*)alloc((size_t)NPAD * 128 * 4);
    unsigned short* h_hi = (unsigned short*)alloc((size_t)NPAD * 128 * 2);
    unsigned short* h_lo = (unsigned short*)alloc((size_t)NPAD * 128 * 2);
    unsigned short* a_hi = (unsigned short*)alloc((size_t)NPAD * 128 * 2);
    unsigned short* a_lo = (unsigned short*)alloc((size_t)NPAD * 128 * 2);
    unsigned short* Wh   = (unsigned short*)alloc((size_t)N_ETYPES * NPAD * 128 * 2);
    unsigned short* GI   = (unsigned short*)alloc((size_t)NPAD * 384 * 2);
    unsigned short* GH   = (unsigned short*)alloc((size_t)NPAD * 384 * 2);
    unsigned short* WeH  = (unsigned short*)alloc((size_t)N_ETYPES * 16384 * 2);
    unsigned short* WeL  = (unsigned short*)alloc((size_t)N_ETYPES * 16384 * 2);
    unsigned short* WihH = (unsigned short*)alloc((size_t)16 * 384 * 8 * 2);
    unsigned short* WihL = (unsigned short*)alloc((size_t)16 * 384 * 8 * 2);
    unsigned short* WhhH = (unsigned short*)alloc((size_t)16 * 384 * 8 * 2);
    unsigned short* WhhL = (unsigned short*)alloc((size_t)16 * 384 * 8 * 2);
    int* deg    = (int*)alloc((size_t)NPAD * 4);
    int* rowptr = (int*)alloc((size_t)(NPAD + 1) * 4);
    int* cursor = (int*)alloc((size_t)NPAD * 4);
    int* eidx   = (int*)alloc((size_t)E_EDGES * 4);
    float* hg   = (float*)alloc((size_t)N_GRAPHS * HID * 4);

    k_init_h<<<(NPAD * HID + 255) / 256, 256, 0, stream>>>(feat, h32, h_hi, h_lo);
    k_prepW<<<(N_ETYPES * 2048 + 2 * 16 * 384 + 255) / 256, 256, 0, stream>>>(
        W_e, W_ih, W_hh, WeH, WeL, WihH, WihL, WhhH, WhhL);
    k_zero<<<(NPAD / 4 + 255) / 256, 256, 0, stream>>>((float*)deg, NPAD / 4);
    k_count<<<(E_EDGES + 255) / 256, 256, 0, stream>>>(dst, deg);
    k_scan<<<1, 1024, 0, stream>>>(deg, rowptr, cursor);
    k_fill<<<(E_EDGES + 255) / 256, 256, 0, stream>>>(src, dst, et, cursor, eidx);

    dim3 gG(118, 3, 2);
    for (int step = 0; step < N_STEPS; ++step) {
        k_egemm<<<118 * N_ETYPES, 256, 0, stream>>>(
            h_hi, h_lo, (const uint4*)WeH, (const uint4*)WeL, b_e, Wh);
        k_agg<<<NPAD / 4, 256, 0, stream>>>(rowptr, eidx, (const unsigned int*)Wh,
                                            (unsigned int*)a_hi, (unsigned int*)a_lo);
        k_ggemm<<<gG, 256, 0, stream>>>(
            a_hi, a_lo, h_hi, h_lo,
            (const uint4*)WihH, (const uint4*)WihL, (const uint4*)WhhH, (const uint4*)WhhL,
            b_ih, b_hh, GI, GH);
        k_gates<<<(N_NODES * 64 + 255) / 256, 256, 0, stream>>>(
            GI, GH, h32, (unsigned int*)h_hi, (unsigned int*)h_lo);
    }

    k_zero<<<(N_GRAPHS * HID / 4 + 255) / 256, 256, 0, stream>>>(hg, N_GRAPHS * HID / 4);
    k_pool<<<(N_NODES * HID + 255) / 256, 256, 0, stream>>>(h32, gid, hg);
    k_cls<<<1, 640, 0, stream>>>(hg, W_cls, b_cls, out);
}

// Round 5
// 582.631 us; speedup vs baseline: 39.1344x; 1.1361x over previous
//
#include <hip/hip_runtime.h>
#include <math.h>

#define N_NODES 15000
#define NPAD    15104      // 118*128
#define E_EDGES 240000
#define IN_DIM  100
#define HID     128
#define N_ETYPES 13
#define N_STEPS  6
#define N_GRAPHS 64
#define N_CLASSES 10

typedef short v8bf __attribute__((ext_vector_type(8)));
typedef float v4f  __attribute__((ext_vector_type(4)));

union FragU { uint4 u; v8bf b; };

static __device__ __forceinline__ float bf2f(unsigned short u) {
    union { unsigned int i; float f; } x; x.i = ((unsigned int)u) << 16; return x.f;
}
static __device__ __forceinline__ unsigned short f2bf(float f) {
    union { float f; unsigned int i; } x; x.f = f;
    unsigned int u = x.i;
    u = (u + 0x7fff + ((u >> 16) & 1)) >> 16;   // round-nearest-even
    return (unsigned short)u;
}
static __device__ __forceinline__ float sigm(float x) { return 1.f / (1.f + expf(-x)); }

// ---------------- misc ----------------
__global__ __launch_bounds__(256) void k_zero(float* __restrict__ p, long n4) {
    long i = (long)blockIdx.x * 256 + threadIdx.x;
    if (i < n4) ((float4*)p)[i] = make_float4(0.f, 0.f, 0.f, 0.f);
}

__global__ __launch_bounds__(256) void k_init_h(const float* __restrict__ feat,
                                                float* __restrict__ h32,
                                                unsigned short* __restrict__ h_hi,
                                                unsigned short* __restrict__ h_lo) {
    int idx = blockIdx.x * 256 + threadIdx.x;
    if (idx >= NPAD * HID) return;
    int n = idx >> 7, c = idx & 127;
    float v = 0.f;
    if (n < N_NODES && c < IN_DIM) v = feat[n * IN_DIM + c];
    h32[idx] = v;
    unsigned short hi = f2bf(v);
    h_hi[idx] = hi;
    h_lo[idx] = f2bf(v - bf2f(hi));
}

// Weights -> bf16 hi/lo MFMA-fragment planes.
// Frag layout for B[128 x NC]: frag id = kcsub*NC + col (kcsub 0..15), 8 bf16 k=kcsub*8+j.
__global__ __launch_bounds__(256) void k_prepW(
    const float* __restrict__ W_e, const float* __restrict__ W_ih, const float* __restrict__ W_hh,
    unsigned short* __restrict__ WeH, unsigned short* __restrict__ WeL,
    unsigned short* __restrict__ WihH, unsigned short* __restrict__ WihL,
    unsigned short* __restrict__ WhhH, unsigned short* __restrict__ WhhL)
{
    int f = blockIdx.x * 256 + threadIdx.x;
    const int NE = N_ETYPES * 2048;
    const int NG = 16 * 384;
    unsigned short th[8], tl[8];
    if (f < NE) {
        int t = f >> 11, r = f & 2047, kcsub = r >> 7, c = r & 127;
        #pragma unroll
        for (int j = 0; j < 8; ++j) {
            float w = W_e[(long)t * 16384 + (kcsub * 8 + j) * 128 + c];
            th[j] = f2bf(w); tl[j] = f2bf(w - bf2f(th[j]));
        }
        long off = (long)t * 16384 + ((kcsub << 7) + c) * 8;
        *(uint4*)(WeH + off) = *(uint4*)th;
        *(uint4*)(WeL + off) = *(uint4*)tl;
    } else if (f < NE + 2 * NG) {
        int f2 = f - NE;
        const float* srcp = (f2 < NG) ? W_ih : W_hh;
        unsigned short* dh = (f2 < NG) ? WihH : WhhH;
        unsigned short* dl = (f2 < NG) ? WihL : WhhL;
        int g = (f2 < NG) ? f2 : f2 - NG;
        int kcsub = g / 384, c = g - kcsub * 384;
        #pragma unroll
        for (int j = 0; j < 8; ++j) {
            float w = srcp[(long)c * 128 + kcsub * 8 + j];   // B[k][c] = W[c][k]
            th[j] = f2bf(w); tl[j] = f2bf(w - bf2f(th[j]));
        }
        long off = ((long)kcsub * 384 + c) * 8;
        *(uint4*)(dh + off) = *(uint4*)th;
        *(uint4*)(dl + off) = *(uint4*)tl;
    }
}

// ---------------- CSR build ----------------
__global__ __launch_bounds__(256) void k_count(const int* __restrict__ dst, int* __restrict__ deg) {
    int e = blockIdx.x * 256 + threadIdx.x;
    if (e < E_EDGES) atomicAdd(&deg[dst[e]], 1);
}

__global__ __launch_bounds__(1024) void k_scan(const int* __restrict__ deg,
                                               int* __restrict__ rowptr, int* __restrict__ cursor) {
    __shared__ int part[1024];
    int tid = threadIdx.x;
    const int CH = 15;
    int base = tid * CH;
    int local[CH]; int s = 0;
    #pragma unroll
    for (int i = 0; i < CH; ++i) {
        int d = (base + i < NPAD) ? deg[base + i] : 0;
        local[i] = s; s += d;
    }
    part[tid] = s; __syncthreads();
    for (int off = 1; off < 1024; off <<= 1) {
        int v = (tid >= off) ? part[tid - off] : 0;
        __syncthreads();
        part[tid] += v;
        __syncthreads();
    }
    int excl = (tid > 0) ? part[tid - 1] : 0;
    #pragma unroll
    for (int i = 0; i < CH; ++i)
        if (base + i < NPAD) { rowptr[base + i] = excl + local[i]; cursor[base + i] = excl + local[i]; }
    if (tid == 0) rowptr[NPAD] = part[1023];
}

__global__ __launch_bounds__(256) void k_fill(const int* __restrict__ src, const int* __restrict__ dst,
                                              const int* __restrict__ et, int* __restrict__ cursor,
                                              int* __restrict__ eidx) {
    int e = blockIdx.x * 256 + threadIdx.x;
    if (e >= E_EDGES) return;
    int d = dst[e];
    int pos = atomicAdd(&cursor[d], 1);
    eidx[pos] = et[e] * NPAD + src[e];
}

// ---------------- etype GEMM: Wh[t] = h @ W_e[t] + b_e[t] ----------------
// 512 thr = 8 waves; block = 128 rows x 128 cols, one etype; B hi/lo staged in LDS (64 KB).
__global__ __launch_bounds__(512) void k_egemm(
    const unsigned short* __restrict__ Ahi, const unsigned short* __restrict__ Alo,
    const uint4* __restrict__ BH, const uint4* __restrict__ BL,
    const float* __restrict__ bias, unsigned short* __restrict__ C)
{
    __shared__ uint4 blds[2][2048];          // 64 KB
    const int NW = 118 * N_ETYPES;           // 1534
    const int q = NW / 8, r8 = NW % 8;
    int bid = blockIdx.x;
    int xcd = bid & 7, ii = bid >> 3;
    int lid = (xcd < r8 ? xcd * (q + 1) : r8 * (q + 1) + (xcd - r8) * q) + ii;
    int rg = lid / N_ETYPES, t = lid - rg * N_ETYPES;

    int tid = threadIdx.x;
    {
        const uint4* bh = BH + t * 2048;
        const uint4* bl = BL + t * 2048;
        #pragma unroll
        for (int it = 0; it < 4; ++it) {
            int f = it * 512 + tid;
            blds[0][f] = bh[f];
            blds[1][f] = bl[f];
        }
    }
    __syncthreads();

    int lane = tid & 63, w = tid >> 6;
    int r0 = rg * 128 + w * 16;
    int l15 = lane & 15, lsub = lane >> 4;

    FragU ah[4], al[4];
    const char* Ahb = (const char*)Ahi;
    const char* Alb = (const char*)Alo;
    #pragma unroll
    for (int kc = 0; kc < 4; ++kc) {
        long boff = (long)(r0 + l15) * 256 + kc * 64 + lsub * 16;
        ah[kc].u = *(const uint4*)(Ahb + boff);
        al[kc].u = *(const uint4*)(Alb + boff);
    }

    v4f acc[8];
    #pragma unroll
    for (int c8 = 0; c8 < 8; ++c8) acc[c8] = (v4f)(0.f);

    #pragma unroll
    for (int kc = 0; kc < 4; ++kc)
        #pragma unroll
        for (int c8 = 0; c8 < 8; ++c8) {
            int bi = (kc * 4 + lsub) * 128 + c8 * 16 + l15;
            FragU bhf, blf; bhf.u = blds[0][bi]; blf.u = blds[1][bi];
            acc[c8] = __builtin_amdgcn_mfma_f32_16x16x32_bf16(ah[kc].b, bhf.b, acc[c8], 0, 0, 0);
            acc[c8] = __builtin_amdgcn_mfma_f32_16x16x32_bf16(al[kc].b, bhf.b, acc[c8], 0, 0, 0);
            acc[c8] = __builtin_amdgcn_mfma_f32_16x16x32_bf16(ah[kc].b, blf.b, acc[c8], 0, 0, 0);
        }

    const float* bs = bias + t * 128;
    unsigned short* Ct = C + (long)t * NPAD * 128;
    int rbase = r0 + lsub * 4;               // C/D: col = lane&15, row = lsub*4 + i
    #pragma unroll
    for (int c8 = 0; c8 < 8; ++c8) {
        int col = c8 * 16 + l15;
        float bv = bs[col];
        #pragma unroll
        for (int i = 0; i < 4; ++i) {
            int row = rbase + i;
            if (row < N_NODES) Ct[(long)row * 128 + col] = f2bf(acc[c8][i] + bv);
        }
    }
}

// ---------------- GRU GEMMs: z=0: GI = a@WihT, z=1: GH = h@WhhT (bf16 out) ----------------
// 512 thr = 8 waves; block = 128 rows x 128 cols (y selects col slice); B slice in LDS.
__global__ __launch_bounds__(512) void k_ggemm(
    const unsigned short* __restrict__ A0h, const unsigned short* __restrict__ A0l,
    const unsigned short* __restrict__ A1h, const unsigned short* __restrict__ A1l,
    const uint4* __restrict__ B0H, const uint4* __restrict__ B0L,
    const uint4* __restrict__ B1H, const uint4* __restrict__ B1L,
    const float* __restrict__ bias0, const float* __restrict__ bias1,
    unsigned short* __restrict__ C0, unsigned short* __restrict__ C1)
{
    __shared__ uint4 blds[2][2048];          // 64 KB
    int z = blockIdx.z;
    const unsigned short* Ahi = z ? A1h : A0h;
    const unsigned short* Alo = z ? A1l : A0l;
    const uint4* BH = z ? B1H : B0H;
    const uint4* BL = z ? B1L : B0L;
    const float* bias = z ? bias1 : bias0;
    unsigned short* C = z ? C1 : C0;
    int j0 = blockIdx.y * 128;

    int tid = threadIdx.x;
    {
        #pragma unroll
        for (int it = 0; it < 4; ++it) {
            int f = it * 512 + tid;
            int kcsub = f >> 7, c = f & 127;
            int gi = kcsub * 384 + j0 + c;
            blds[0][f] = BH[gi];
            blds[1][f] = BL[gi];
        }
    }
    __syncthreads();

    int lane = tid & 63, w = tid >> 6;
    int r0 = blockIdx.x * 128 + w * 16;
    int l15 = lane & 15, lsub = lane >> 4;

    FragU ah[4], al[4];
    const char* Ahb = (const char*)Ahi;
    const char* Alb = (const char*)Alo;
    #pragma unroll
    for (int kc = 0; kc < 4; ++kc) {
        long boff = (long)(r0 + l15) * 256 + kc * 64 + lsub * 16;
        ah[kc].u = *(const uint4*)(Ahb + boff);
        al[kc].u = *(const uint4*)(Alb + boff);
    }

    v4f acc[8];
    #pragma unroll
    for (int c8 = 0; c8 < 8; ++c8) acc[c8] = (v4f)(0.f);

    #pragma unroll
    for (int kc = 0; kc < 4; ++kc)
        #pragma unroll
        for (int c8 = 0; c8 < 8; ++c8) {
            int bi = (kc * 4 + lsub) * 128 + c8 * 16 + l15;
            FragU bhf, blf; bhf.u = blds[0][bi]; blf.u = blds[1][bi];
            acc[c8] = __builtin_amdgcn_mfma_f32_16x16x32_bf16(ah[kc].b, bhf.b, acc[c8], 0, 0, 0);
            acc[c8] = __builtin_amdgcn_mfma_f32_16x16x32_bf16(al[kc].b, bhf.b, acc[c8], 0, 0, 0);
            acc[c8] = __builtin_amdgcn_mfma_f32_16x16x32_bf16(ah[kc].b, blf.b, acc[c8], 0, 0, 0);
        }

    int rbase = r0 + lsub * 4;
    #pragma unroll
    for (int c8 = 0; c8 < 8; ++c8) {
        int col = j0 + c8 * 16 + l15;
        float bv = bias[col];
        #pragma unroll
        for (int i = 0; i < 4; ++i) {
            int row = rbase + i;
            if (row < N_NODES) C[(long)row * 384 + col] = f2bf(acc[c8][i] + bv);
        }
    }
}

// ---------------- CSR aggregation: a[d] = sum Wh[eidx] (bf16 in, fp32 acc, hi/lo out) ----------------
__global__ __launch_bounds__(256) void k_agg(
    const int* __restrict__ rowptr, const int* __restrict__ eidx,
    const unsigned int* __restrict__ Wh,                 // bf16 pairs
    unsigned int* __restrict__ a_hi, unsigned int* __restrict__ a_lo)
{
    int d = blockIdx.x * 4 + (threadIdx.x >> 6);
    if (d >= NPAD) return;
    int lane = threadIdx.x & 63;
    int s = rowptr[d], e = rowptr[d + 1];
    float a0 = 0.f, a1 = 0.f, b0 = 0.f, b1 = 0.f;
    int i = s;
    for (; i + 3 < e; i += 4) {
        int w0 = eidx[i], w1 = eidx[i + 1], w2 = eidx[i + 2], w3 = eidx[i + 3];
        unsigned int v0 = Wh[(long)w0 * 64 + lane];
        unsigned int v1 = Wh[(long)w1 * 64 + lane];
        unsigned int v2 = Wh[(long)w2 * 64 + lane];
        unsigned int v3 = Wh[(long)w3 * 64 + lane];
        a0 += bf2f((unsigned short)(v0 & 0xffff)) + bf2f((unsigned short)(v2 & 0xffff));
        a1 += bf2f((unsigned short)(v0 >> 16))    + bf2f((unsigned short)(v2 >> 16));
        b0 += bf2f((unsigned short)(v1 & 0xffff)) + bf2f((unsigned short)(v3 & 0xffff));
        b1 += bf2f((unsigned short)(v1 >> 16))    + bf2f((unsigned short)(v3 >> 16));
    }
    for (; i < e; ++i) {
        unsigned int v0 = Wh[(long)eidx[i] * 64 + lane];
        a0 += bf2f((unsigned short)(v0 & 0xffff));
        a1 += bf2f((unsigned short)(v0 >> 16));
    }
    a0 += b0; a1 += b1;
    unsigned short h0 = f2bf(a0), h1 = f2bf(a1);
    unsigned short l0 = f2bf(a0 - bf2f(h0)), l1 = f2bf(a1 - bf2f(h1));
    a_hi[(long)d * 64 + lane] = (unsigned int)h0 | ((unsigned int)h1 << 16);
    a_lo[(long)d * 64 + lane] = (unsigned int)l0 | ((unsigned int)l1 << 16);
}

// ---------------- GRU gates (fp32 carry; bf16 hi/lo planes out) ----------------
__global__ __launch_bounds__(256) void k_gates(
    const unsigned short* __restrict__ GI, const unsigned short* __restrict__ GH,
    float* __restrict__ h32,
    unsigned int* __restrict__ h_hi, unsigned int* __restrict__ h_lo)
{
    int idx = blockIdx.x * 256 + threadIdx.x;       // one uint = 2 channels
    if (idx >= N_NODES * 64) return;
    int n = idx >> 6, c2 = idx & 63;
    const unsigned int* gi = (const unsigned int*)(GI + (long)n * 384);
    const unsigned int* gh = (const unsigned int*)(GH + (long)n * 384);
    unsigned int uir = gi[c2], uiz = gi[c2 + 64], uin = gi[c2 + 128];
    unsigned int uhr = gh[c2], uhz = gh[c2 + 64], uhn = gh[c2 + 128];
    float2 ho = ((float2*)h32)[idx];
    float hv[2];
    #pragma unroll
    for (int p = 0; p < 2; ++p) {
        int sh = p * 16;
        float ir = bf2f((unsigned short)(uir >> sh)), iz = bf2f((unsigned short)(uiz >> sh)),
              inn = bf2f((unsigned short)(uin >> sh));
        float hr = bf2f((unsigned short)(uhr >> sh)), hz = bf2f((unsigned short)(uhz >> sh)),
              hn = bf2f((unsigned short)(uhn >> sh));
        float rr = sigm(ir + hr);
        float zg = sigm(iz + hz);
        float ng = tanhf(inn + rr * hn);
        float hov = p ? ho.y : ho.x;
        hv[p] = (1.f - zg) * ng + zg * hov;
    }
    ((float2*)h32)[idx] = make_float2(hv[0], hv[1]);
    unsigned short hi0 = f2bf(hv[0]), hi1 = f2bf(hv[1]);
    h_hi[idx] = (unsigned int)hi0 | ((unsigned int)hi1 << 16);
    unsigned short lo0 = f2bf(hv[0] - bf2f(hi0)), lo1 = f2bf(hv[1] - bf2f(hi1));
    h_lo[idx] = (unsigned int)lo0 | ((unsigned int)lo1 << 16);
}

// ---------------- pooling + classifier ----------------
__global__ __launch_bounds__(256) void k_pool(const float* __restrict__ h32,
                                              const int* __restrict__ gid,
                                              float* __restrict__ hg) {
    int idx = blockIdx.x * 256 + threadIdx.x;
    if (idx >= N_NODES * HID) return;
    int n = idx >> 7, c = idx & 127;
    atomicAdd(&hg[gid[n] * HID + c], h32[idx]);
}

__global__ __launch_bounds__(640) void k_cls(const float* __restrict__ hg,
                                             const float* __restrict__ Wc,
                                             const float* __restrict__ bc,
                                             float* __restrict__ out) {
    int tid = threadIdx.x;
    if (tid >= N_GRAPHS * N_CLASSES) return;
    int g = tid / N_CLASSES, c = tid - g * N_CLASSES;
    float s = bc[c];
    for (int k = 0; k < HID; ++k) s = fmaf(hg[g * HID + k], Wc[c * HID + k], s);
    out[tid] = s;
}

// ---------------- launch ----------------
extern "C" void kernel_launch(void* const* d_in, const int* in_sizes, int n_in,
                              void* d_out, int out_size, void* d_ws, size_t ws_size,
                              hipStream_t stream) {
    const float* feat  = (const float*)d_in[0];
    const int*   src   = (const int*)d_in[1];
    const int*   dst   = (const int*)d_in[2];
    const int*   et    = (const int*)d_in[3];
    const int*   gid   = (const int*)d_in[4];
    const float* W_e   = (const float*)d_in[5];
    const float* b_e   = (const float*)d_in[6];
    const float* W_ih  = (const float*)d_in[7];
    const float* W_hh  = (const float*)d_in[8];
    const float* b_ih  = (const float*)d_in[9];
    const float* b_hh  = (const float*)d_in[10];
    const float* W_cls = (const float*)d_in[11];
    const float* b_cls = (const float*)d_in[12];
    float* out = (float*)d_out;

    char* p = (char*)d_ws;
    auto alloc = [&](size_t bytes) { char* r = p; p += (bytes + 255) & ~(size_t)255; return r; };
    float*          h32  = (float*)alloc((size_t)NPAD * 128 * 4);
    unsigned short* h_hi = (unsigned short*)alloc((size_t)NPAD * 128 * 2);
    unsigned short* h_lo = (unsigned short*)alloc((size_t)NPAD * 128 * 2);
    unsigned short* a_hi = (unsigned short*)alloc((size_t)NPAD * 128 * 2);
    unsigned short* a_lo = (unsigned short*)alloc((size_t)NPAD * 128 * 2);
    unsigned short* Wh   = (unsigned short*)alloc((size_t)N_ETYPES * NPAD * 128 * 2);
    unsigned short* GI   = (unsigned short*)alloc((size_t)NPAD * 384 * 2);
    unsigned short* GH   = (unsigned short*)alloc((size_t)NPAD * 384 * 2);
    unsigned short* WeH  = (unsigned short*)alloc((size_t)N_ETYPES * 16384 * 2);
    unsigned short* WeL  = (unsigned short*)alloc((size_t)N_ETYPES * 16384 * 2);
    unsigned short* WihH = (unsigned short*)alloc((size_t)16 * 384 * 8 * 2);
    unsigned short* WihL = (unsigned short*)alloc((size_t)16 * 384 * 8 * 2);
    unsigned short* WhhH = (unsigned short*)alloc((size_t)16 * 384 * 8 * 2);
    unsigned short* WhhL = (unsigned short*)alloc((size_t)16 * 384 * 8 * 2);
    int* deg    = (int*)alloc((size_t)NPAD * 4);
    int* rowptr = (int*)alloc((size_t)(NPAD + 1) * 4);
    int* cursor = (int*)alloc((size_t)NPAD * 4);
    int* eidx   = (int*)alloc((size_t)E_EDGES * 4);
    float* hg   = (float*)alloc((size_t)N_GRAPHS * HID * 4);

    k_init_h<<<(NPAD * HID + 255) / 256, 256, 0, stream>>>(feat, h32, h_hi, h_lo);
    k_prepW<<<(N_ETYPES * 2048 + 2 * 16 * 384 + 255) / 256, 256, 0, stream>>>(
        W_e, W_ih, W_hh, WeH, WeL, WihH, WihL, WhhH, WhhL);
    k_zero<<<(NPAD / 4 + 255) / 256, 256, 0, stream>>>((float*)deg, NPAD / 4);
    k_count<<<(E_EDGES + 255) / 256, 256, 0, stream>>>(dst, deg);
    k_scan<<<1, 1024, 0, stream>>>(deg, rowptr, cursor);
    k_fill<<<(E_EDGES + 255) / 256, 256, 0, stream>>>(src, dst, et, cursor, eidx);

    dim3 gG(118, 3, 2);
    for (int step = 0; step < N_STEPS; ++step) {
        k_egemm<<<118 * N_ETYPES, 512, 0, stream>>>(
            h_hi, h_lo, (const uint4*)WeH, (const uint4*)WeL, b_e, Wh);
        k_agg<<<NPAD / 4, 256, 0, stream>>>(rowptr, eidx, (const unsigned int*)Wh,
                                            (unsigned int*)a_hi, (unsigned int*)a_lo);
        k_ggemm<<<gG, 512, 0, stream>>>(
            a_hi, a_lo, h_hi, h_lo,
            (const uint4*)WihH, (const uint4*)WihL, (const uint4*)WhhH, (const uint4*)WhhL,
            b_ih, b_hh, GI, GH);
        k_gates<<<(N_NODES * 64 + 255) / 256, 256, 0, stream>>>(
            GI, GH, h32, (unsigned int*)h_hi, (unsigned int*)h_lo);
    }

    k_zero<<<(N_GRAPHS * HID / 4 + 255) / 256, 256, 0, stream>>>(hg, N_GRAPHS * HID / 4);
    k_pool<<<(N_NODES * HID + 255) / 256, 256, 0, stream>>>(h32, gid, hg);
    k_cls<<<1, 640, 0, stream>>>(hg, W_cls, b_cls, out);
}